// Round 5
// baseline (50.376 us; speedup 1.0000x reference)
//
#include <hip/hip_runtime.h>

// InvariantPolynomial: out = sum_e xl[oi[e]] * xr[e] * f(|pos_e|)
// f depends only on d=|pos| (sh[:,:1]==1). R5: SINGLE fused kernel.
//  - per-block 132-entry Catmull-Rom cubic LUT over d in [-h, 5+2h]
//    (h=5/128; rel err ~9e-5 << 2e-2 tol; f==0 in fp32 beyond d=5)
//  - W1/W2 staged to LDS (wave-uniform broadcast reads in build loop)
//  - one float atomicAdd(d_out) per block; d_out zeroed via hipMemsetAsync
//  - no __threadfence (R2: device-scope fence per block cost ~40us)

#define TPB   256
#define TILE  1024          // edges per block
#define TNL   128           // lut resolution over [0,5]
#define TNLP  132           // + pad for cubic taps

// 1/sqrt(E[silu(z)^2]); matched reference exactly (absmax 0.0, R1-R4)
__device__ __constant__ float kSiluCst = 1.6765581f;

__global__ __launch_bounds__(TPB) void fused_edge_kernel(
    const float* __restrict__ pos, const float* __restrict__ xr,
    const float* __restrict__ xl, const int* __restrict__ oi,
    const float* __restrict__ W1, const float* __restrict__ W2,
    float* __restrict__ out, int E)
{
    __shared__ float sW1[600];
    __shared__ float sW2[150];
    __shared__ float lut[TNLP];
    __shared__ double swv[TPB / 64];

    const int  tid   = threadIdx.x;
    const long tile0 = (long)blockIdx.x * TILE;
    const int  rem   = (int)min((long)TILE, (long)E - tile0);
    const int  e0    = tid * 4;
    const bool full  = (e0 + 4 <= rem);

    // ---- issue edge-stream loads early (latency hides under LUT build) ----
    float4 pa, pb, pc, xv; int4 ov;
    if (full) {
        const float4* p4 = (const float4*)(pos + tile0 * 3);
        pa = p4[3 * tid + 0];
        pb = p4[3 * tid + 1];
        pc = p4[3 * tid + 2];
        xv = ((const float4*)(xr + tile0))[tid];
        ov = ((const int4*)(oi + tile0))[tid];
    }

    // ---- stage weights to LDS ----
    if (tid < 200) {
        sW1[tid]       = W1[tid];
        sW1[tid + 200] = W1[tid + 200];
        sW1[tid + 400] = W1[tid + 400];
    }
    if (tid < 150) sW2[tid] = W2[tid];
    __syncthreads();

    // ---- build 132-entry LUT: entry k holds f((k-1)*h) ----
    if (tid < TNLP) {
        const float h   = 5.0f / (float)TNL;
        const float d   = ((float)tid - 1.0f) * h;
        const float t6  = 6.0f * d;                    // gaussian centers at 1..20
        const float w1s = 1.0f / (1.12f * sqrtf(20.0f));
        float emb[20];
        #pragma unroll
        for (int j = 0; j < 20; ++j) {
            float df = t6 - (float)(j + 1);
            emb[j] = __expf(-df * df) * w1s;
        }
        float facc = 0.0f;
        for (int k = 0; k < 30; ++k) {                 // sW1 reads wave-uniform
            float a = 0.0f;
            #pragma unroll
            for (int j = 0; j < 20; ++j) a = fmaf(emb[j], sW1[j * 30 + k], a);
            float s   = a / (1.0f + __expf(-a));       // silu
            float w2s = sW2[k*5+0] + sW2[k*5+1] + sW2[k*5+2] + sW2[k*5+3] + sW2[k*5+4];
            facc = fmaf(s, w2s, facc);
        }
        lut[tid] = facc * (kSiluCst / sqrtf(30.0f));
    }
    __syncthreads();

    // ---- consume 4 edges/thread ----
    const float invh = (float)TNL / 5.0f;
    const float umax = (float)(TNL + 1) + 0.999f;      // taps stay <= TNLP-1
    double acc = 0.0;

    if (full) {
        float px[4] = {pa.x, pa.w, pb.z, pc.y};
        float py[4] = {pa.y, pb.x, pb.w, pc.z};
        float pz[4] = {pa.z, pb.y, pc.x, pc.w};
        float xrv[4] = {xv.x, xv.y, xv.z, xv.w};
        float xlv[4];
        xlv[0] = xl[ov.x]; xlv[1] = xl[ov.y]; xlv[2] = xl[ov.z]; xlv[3] = xl[ov.w];

        float fsum = 0.0f;
        #pragma unroll
        for (int j = 0; j < 4; ++j) {
            float d = sqrtf(fmaf(px[j], px[j], fmaf(py[j], py[j], pz[j] * pz[j])));
            float u = fminf(fmaf(d, invh, 1.0f), umax);
            int   i0 = (int)u;
            float t  = u - (float)i0;
            float p0 = lut[i0 - 1], p1 = lut[i0], p2 = lut[i0 + 1], p3 = lut[i0 + 2];
            float w0 = 0.5f * t * ((2.0f - t) * t - 1.0f);
            float w1 = 0.5f * (t * t * (3.0f * t - 5.0f) + 2.0f);
            float w2 = 0.5f * t * ((4.0f - 3.0f * t) * t + 1.0f);
            float w3 = 0.5f * t * t * (t - 1.0f);
            float f  = w0 * p0 + w1 * p1 + w2 * p2 + w3 * p3;
            fsum = fmaf(f * xrv[j], xlv[j], fsum);
        }
        acc = (double)fsum;
    } else if (e0 < rem) {
        float fsum = 0.0f;
        for (int j = 0; j < 4 && e0 + j < rem; ++j) {
            long  ge = tile0 + e0 + j;
            float x = pos[3 * ge], y = pos[3 * ge + 1], z = pos[3 * ge + 2];
            float d = sqrtf(fmaf(x, x, fmaf(y, y, z * z)));
            float u = fminf(fmaf(d, invh, 1.0f), umax);
            int   i0 = (int)u;
            float t  = u - (float)i0;
            float p0 = lut[i0 - 1], p1 = lut[i0], p2 = lut[i0 + 1], p3 = lut[i0 + 2];
            float w0 = 0.5f * t * ((2.0f - t) * t - 1.0f);
            float w1 = 0.5f * (t * t * (3.0f * t - 5.0f) + 2.0f);
            float w2 = 0.5f * t * ((4.0f - 3.0f * t) * t + 1.0f);
            float w3 = 0.5f * t * t * (t - 1.0f);
            float f  = w0 * p0 + w1 * p1 + w2 * p2 + w3 * p3;
            fsum = fmaf(f * xr[ge], xl[oi[ge]], fsum);
        }
        acc = (double)fsum;
    }

    // ---- deterministic block reduction, then one atomic per block ----
    #pragma unroll
    for (int off = 32; off > 0; off >>= 1) acc += __shfl_down(acc, off);
    int lane = tid & 63, wv = tid >> 6;
    if (lane == 0) swv[wv] = acc;
    __syncthreads();
    if (tid == 0) {
        double bsum = (swv[0] + swv[1]) + (swv[2] + swv[3]);
        atomicAdd(out, (float)bsum);
    }
}

extern "C" void kernel_launch(void* const* d_in, const int* in_sizes, int n_in,
                              void* d_out, int out_size, void* d_ws, size_t ws_size,
                              hipStream_t stream) {
    const float* pos = (const float*)d_in[0];   // [E,3]
    const float* xr  = (const float*)d_in[1];   // [E,1]
    const float* xl  = (const float*)d_in[2];   // [N,1]
    const float* W1  = (const float*)d_in[3];   // [20,30]
    const float* W2  = (const float*)d_in[4];   // [30,5]
    const int*   oi  = (const int*)d_in[5];     // [E]
    float* out = (float*)d_out;

    int E = in_sizes[1];
    int nblk = (E + TILE - 1) / TILE;           // 1954 for E=2M

    hipMemsetAsync(out, 0, sizeof(float), stream);
    hipLaunchKernelGGL(fused_edge_kernel, dim3(nblk), dim3(TPB), 0, stream,
                       pos, xr, xl, oi, W1, W2, out, E);
}

// Round 6
// 28.027 us; speedup vs baseline: 1.7974x; 1.7974x over previous
//
#include <hip/hip_runtime.h>

// InvariantPolynomial: out = sum_e xl[oi[e]] * xr[e] * f(|pos_e|)
// f depends only on d=|pos| (sh[:,:1]==1); 2048-entry linear LUT over [0,5]
// (f==0 in fp32 beyond d=5; rel err ~1e-4 << 2e-2 tol).
//
// R6: two dispatches only.
//  - build_lut_kernel: global 8KB LUT (built ONCE, not per block -- R5 lesson:
//    per-block rebuild = 3x the edge work) + zeroes out[0] (kills memset node).
//  - edge_sum_kernel: 8 edges/thread register-direct vector loads, LDS LUT,
//    fp32 inner accum, double reduce, ONE float atomicAdd per block.
//    No __threadfence (R2), no partials/final_reduce (graph-gap cost).
//
// ws layout: [0,8KB) float LUT.

#define TN    2048
#define DMAXF 5.0f
#define TPB   256
#define EPT   8
#define TILE  (TPB * EPT)   // 2048 edges per block

// 1/sqrt(E[silu(z)^2]); matched reference exactly (absmax 0.0, R1-R5)
__device__ __constant__ float kSiluCst = 1.6765581f;

__global__ __launch_bounds__(256) void build_lut_kernel(
    const float* __restrict__ W1, const float* __restrict__ W2,
    float* __restrict__ table, float* __restrict__ out)
{
    if (blockIdx.x == 0 && threadIdx.x == 0) out[0] = 0.0f;  // replay-safe reset

    // 32 lanes per LUT entry: lane k in [0,30) computes hidden unit k.
    int t = blockIdx.x * 256 + threadIdx.x;
    int entry = t >> 5;
    int k = t & 31;
    int kk = (k < 30) ? k : 29;

    float d  = (float)entry * (DMAXF / (float)TN);
    float t6 = 6.0f * d;                      // gaussian centers at t6 = 1..20
    const float w1scale = 1.0f / (1.12f * sqrtf(20.0f));

    float a = 0.0f;
    #pragma unroll
    for (int j = 0; j < 20; ++j) {
        float df = t6 - (float)(j + 1);
        float e  = __expf(-df * df);
        a = fmaf(e * w1scale, W1[j * 30 + kk], a);
    }
    float s = a / (1.0f + __expf(-a));        // silu

    float w2s = 0.0f;
    #pragma unroll
    for (int c = 0; c < 5; ++c) w2s += W2[kk * 5 + c];

    float contrib = (k < 30) ? s * w2s * (kSiluCst / sqrtf(30.0f)) : 0.0f;

    #pragma unroll
    for (int m = 16; m > 0; m >>= 1) contrib += __shfl_xor(contrib, m, 32);

    if (k == 0 && entry < TN) table[entry] = contrib;
}

__global__ __launch_bounds__(TPB) void edge_sum_kernel(
    const float* __restrict__ pos, const float* __restrict__ xr,
    const float* __restrict__ xl, const int* __restrict__ oi,
    const float* __restrict__ table, float* __restrict__ out, int E)
{
    __shared__ float lut[TN];
    __shared__ double swv[TPB / 64];

    const int tid = threadIdx.x;

    {   // stage 8KB LUT: 2 float4 per thread (source is L2/L3-resident)
        const float4* t4 = (const float4*)table;
        float4* l4 = (float4*)lut;
        l4[tid]       = t4[tid];
        l4[tid + TPB] = t4[tid + TPB];
    }
    __syncthreads();

    const float scale = (float)TN / DMAXF;
    const float umax  = (float)(TN - 1) - 1e-3f;

    const long tile0 = (long)blockIdx.x * TILE;
    const int  rem   = (int)min((long)TILE, (long)E - tile0);
    const int  e0    = tid * EPT;
    double acc = 0.0;

    if (e0 + EPT <= rem) {
        const long g0 = tile0 + e0;                 // multiple of 8 -> aligned
        // 6 float4 = this thread's 8 edges of pos
        const float4* p4 = (const float4*)(pos + g0 * 3);
        float4 P0 = p4[0], P1 = p4[1], P2 = p4[2], P3 = p4[3], P4 = p4[4], P5 = p4[5];
        const float4* x4 = (const float4*)(xr + g0);
        float4 X0 = x4[0], X1 = x4[1];
        const int4* o4 = (const int4*)(oi + g0);
        int4 O0 = o4[0], O1 = o4[1];

        // 8 independent gathers in flight (MLP)
        float xlv[EPT];
        xlv[0] = xl[O0.x]; xlv[1] = xl[O0.y]; xlv[2] = xl[O0.z]; xlv[3] = xl[O0.w];
        xlv[4] = xl[O1.x]; xlv[5] = xl[O1.y]; xlv[6] = xl[O1.z]; xlv[7] = xl[O1.w];

        float px[EPT] = {P0.x, P0.w, P1.z, P2.y, P3.x, P3.w, P4.z, P5.y};
        float py[EPT] = {P0.y, P1.x, P1.w, P2.z, P3.y, P4.x, P4.w, P5.z};
        float pz[EPT] = {P0.z, P1.y, P2.x, P2.w, P3.z, P4.y, P5.x, P5.w};
        float xrv[EPT] = {X0.x, X0.y, X0.z, X0.w, X1.x, X1.y, X1.z, X1.w};

        float fsum = 0.0f;
        #pragma unroll
        for (int j = 0; j < EPT; ++j) {
            float d  = sqrtf(fmaf(px[j], px[j], fmaf(py[j], py[j], pz[j] * pz[j])));
            float u  = fminf(d * scale, umax);
            int   i0 = (int)u;
            float fr = u - (float)i0;
            float f  = fmaf(fr, lut[i0 + 1] - lut[i0], lut[i0]);
            fsum = fmaf(f * xrv[j], xlv[j], fsum);
        }
        acc = (double)fsum;
    } else if (e0 < rem) {
        // guarded scalar tail (last block only)
        float fsum = 0.0f;
        for (int j = 0; j < EPT && e0 + j < rem; ++j) {
            long  ge = tile0 + e0 + j;
            float x = pos[3 * ge], y = pos[3 * ge + 1], z = pos[3 * ge + 2];
            float d  = sqrtf(fmaf(x, x, fmaf(y, y, z * z)));
            float u  = fminf(d * scale, umax);
            int   i0 = (int)u;
            float fr = u - (float)i0;
            float f  = fmaf(fr, lut[i0 + 1] - lut[i0], lut[i0]);
            fsum = fmaf(f * xr[ge], xl[oi[ge]], fsum);
        }
        acc = (double)fsum;
    }

    // deterministic block reduction (wave shfl + LDS across 4 waves)
    #pragma unroll
    for (int off = 32; off > 0; off >>= 1) acc += __shfl_down(acc, off);
    int lane = tid & 63, wv = tid >> 6;
    if (lane == 0) swv[wv] = acc;
    __syncthreads();
    if (tid == 0) {
        double bsum = (swv[0] + swv[1]) + (swv[2] + swv[3]);
        atomicAdd(out, (float)bsum);   // ~977 atomics to one line: negligible
    }
}

extern "C" void kernel_launch(void* const* d_in, const int* in_sizes, int n_in,
                              void* d_out, int out_size, void* d_ws, size_t ws_size,
                              hipStream_t stream) {
    const float* pos = (const float*)d_in[0];   // [E,3]
    const float* xr  = (const float*)d_in[1];   // [E,1]
    const float* xl  = (const float*)d_in[2];   // [N,1]
    const float* W1  = (const float*)d_in[3];   // [20,30]
    const float* W2  = (const float*)d_in[4];   // [30,5]
    const int*   oi  = (const int*)d_in[5];     // [E]
    float* out = (float*)d_out;

    int E = in_sizes[1];
    int nblk = (E + TILE - 1) / TILE;           // 977 for E=2M

    float* table = (float*)d_ws;

    hipLaunchKernelGGL(build_lut_kernel, dim3((TN * 32) / 256), dim3(256), 0, stream,
                       W1, W2, table, out);
    hipLaunchKernelGGL(edge_sum_kernel, dim3(nblk), dim3(TPB), 0, stream,
                       pos, xr, xl, oi, table, out, E);
}